// Round 8
// baseline (256.033 us; speedup 1.0000x reference)
//
#include <hip/hip_runtime.h>
#include <cstddef>

// Problem constants
constexpr int B_ = 4, H_ = 96, W_ = 96, C_ = 192, QKVC = 576;
constexpr int NPIX = B_ * H_ * W_;           // 36864
constexpr float SCALE = 0.17677669529663689f; // 32^-0.5

typedef __attribute__((ext_vector_type(8))) short bf16x8;
typedef __attribute__((ext_vector_type(4))) float f32x4;
typedef unsigned short ushort_t;

__device__ __forceinline__ unsigned short f2bf(float f) {
    unsigned int u = __builtin_bit_cast(unsigned int, f);
    u += 0x7fffu + ((u >> 16) & 1u);       // round-to-nearest-even
    return (unsigned short)(u >> 16);
}
__device__ __forceinline__ float bf2f(unsigned short h) {
    unsigned int u = ((unsigned int)h) << 16;
    return __builtin_bit_cast(float, u);
}
__device__ __forceinline__ unsigned int pack2(unsigned short a, unsigned short b) {
    return (unsigned int)a | ((unsigned int)b << 16);
}

// ---------------------------------------------------------------------------
// convert_x: fp32 -> bf16
// ---------------------------------------------------------------------------
__global__ __launch_bounds__(256) void convert_x_kernel(
    const float* __restrict__ x, ushort_t* __restrict__ xh, int n4)
{
    int i = blockIdx.x * 256 + threadIdx.x;
    if (i >= n4) return;
    float4 v = ((const float4*)x)[i];
    uint2 p;
    p.x = pack2(f2bf(v.x), f2bf(v.y));
    p.y = pack2(f2bf(v.z), f2bf(v.w));
    ((uint2*)xh)[i] = p;
}

// ---------------------------------------------------------------------------
// convert_w: w_qkv -> wqt[576][192] bf16; w_proj -> wpt_h/wpt_l split bf16.
// ---------------------------------------------------------------------------
__global__ __launch_bounds__(256) void convert_w_kernel(
    const float* __restrict__ w_qkv, const float* __restrict__ w_proj,
    ushort_t* __restrict__ wqt, ushort_t* __restrict__ wpt_h,
    ushort_t* __restrict__ wpt_l)
{
    int idx = blockIdx.x * 256 + threadIdx.x;
    if (idx < 576 * 192) {
        int n = idx / 192, k = idx - n * 192;
        wqt[idx] = f2bf(w_qkv[(size_t)k * 576 + n]);
    } else {
        int i2 = idx - 576 * 192;
        if (i2 < 192 * 192) {
            int n = i2 / 192, k = i2 - n * 192;
            float v = w_proj[(size_t)k * 192 + n];
            unsigned short h = f2bf(v);
            wpt_h[i2] = h;
            wpt_l[i2] = f2bf(v - bf2f(h));
        }
    }
}

// ---------------------------------------------------------------------------
// vT transpose: qkvh v-channels -> vT[(b*96+i)*6 + g*2+h][32d][96j] bf16.
// Block = one image row (384 blocks, 192 threads). Coalesced uint4 in/out,
// LDS-tiled transpose ([96 pix][200-pad] bf16).
// ---------------------------------------------------------------------------
__global__ __launch_bounds__(192) void vt_kernel(
    const ushort_t* __restrict__ qkvh, ushort_t* __restrict__ vT)
{
    __shared__ ushort_t lds[96 * 200];     // [pix][g*64+h*32+d], pad to 200

    const int row = blockIdx.x;            // b*96 + i
    const int tid = threadIdx.x;
    const ushort_t* src = qkvh + (size_t)row * 96 * QKVC;

    #pragma unroll
    for (int it = 0; it < 12; ++it) {
        int flat = it * 192 + tid;         // 96 pix x 24 chunks
        int pix = flat / 24, c = flat - pix * 24;
        int g = c >> 3, c8 = c & 7;        // vch = g*64 + c8*8
        uint4 v = *(const uint4*)(src + (size_t)pix * QKVC + g * 192 + 128 + c8 * 8);
        *(uint4*)(&lds[pix * 200 + g * 64 + c8 * 8]) = v;
    }
    __syncthreads();

    ushort_t* dst = vT + (size_t)row * 6 * 3072;
    #pragma unroll
    for (int it = 0; it < 12; ++it) {
        int flat = it * 192 + tid;         // 6 slices x 32 d x 12 j8
        int slice = flat / 384, rem = flat - slice * 384;
        int d = rem / 12, j8 = rem - d * 12;
        int vch = (slice >> 1) * 64 + (slice & 1) * 32 + d;
        uint4 o;
        unsigned short s0 = lds[(j8 * 8 + 0) * 200 + vch];
        unsigned short s1 = lds[(j8 * 8 + 1) * 200 + vch];
        unsigned short s2 = lds[(j8 * 8 + 2) * 200 + vch];
        unsigned short s3 = lds[(j8 * 8 + 3) * 200 + vch];
        unsigned short s4 = lds[(j8 * 8 + 4) * 200 + vch];
        unsigned short s5 = lds[(j8 * 8 + 5) * 200 + vch];
        unsigned short s6 = lds[(j8 * 8 + 6) * 200 + vch];
        unsigned short s7 = lds[(j8 * 8 + 7) * 200 + vch];
        o.x = pack2(s0, s1); o.y = pack2(s2, s3);
        o.z = pack2(s4, s5); o.w = pack2(s6, s7);
        *(uint4*)(dst + (size_t)slice * 3072 + d * 96 + j8 * 8) = o;
    }
}

// ---------------------------------------------------------------------------
// MFMA bf16 GEMM, tile 64x192x64, register-prefetch K-pipeline.
// A bf16 [M][K], B pre-transposed Bt[n][k] (+ low plane if BSPLIT: 2 passes).
// OUTBF: bf16 C via LDS-transpose epilogue (packed uint4 stores);
// else fp32 C via direct coalesced dword stores.
// LDS fragment-order with XOR swizzle: chunk(kc,i) at kc*DIM + (i^kc).
// ---------------------------------------------------------------------------
template<bool BSPLIT, bool OUTBF>
__global__ __launch_bounds__(256) void gemm_mfma3_kernel(
    const ushort_t* __restrict__ A,
    const ushort_t* __restrict__ Bt_h, const ushort_t* __restrict__ Bt_l,
    const float* __restrict__ bias, void* __restrict__ Cout,
    int M, int N, int K)
{
    constexpr int LBYTES = BSPLIT ? (8192 + 2 * 24576) : 32768;
    __shared__ __align__(16) unsigned char Lraw[LBYTES];
    ushort_t* As  = (ushort_t*)Lraw;                   // 8 KB
    ushort_t* Bs0 = (ushort_t*)(Lraw + 8192);          // 24 KB
    ushort_t* Bs1 = (ushort_t*)(Lraw + 8192 + 24576);  // 24 KB (BSPLIT)

    const int tid = threadIdx.x;
    const int lane = tid & 63;
    const int w = tid >> 6;
    const int wm = (w & 1) * 32;
    const int wn = (w >> 1) * 96;
    const int fm = lane & 15;
    const int fq = lane >> 4;

    const int ntiles = N / 192;
    const int m0 = (blockIdx.x / ntiles) * 64;
    const int n0 = (blockIdx.x % ntiles) * 192;

    // staging index decode (shared by prefetch + LDS write)
    const int am = tid >> 3, akc = tid & 7;            // A: it*256+tid -> +32 rows
    const int bn = tid >> 3, bkc = tid & 7;

    f32x4 acc[2][6];
    #pragma unroll
    for (int mi = 0; mi < 2; ++mi)
        #pragma unroll
        for (int ni = 0; ni < 6; ++ni)
            acc[mi][ni] = (f32x4){0.f, 0.f, 0.f, 0.f};

    uint4 pa[2], pb[6], pb2[6];
    #pragma unroll
    for (int it = 0; it < 2; ++it)
        pa[it] = *(const uint4*)(A + (size_t)(m0 + it * 32 + am) * K + akc * 8);
    #pragma unroll
    for (int it = 0; it < 6; ++it) {
        pb[it] = *(const uint4*)(Bt_h + (size_t)(n0 + it * 32 + bn) * K + bkc * 8);
        if constexpr (BSPLIT)
            pb2[it] = *(const uint4*)(Bt_l + (size_t)(n0 + it * 32 + bn) * K + bkc * 8);
    }

    for (int k0 = 0; k0 < K; k0 += 64) {
        // write staged regs -> LDS (prev readers done via tail barrier)
        #pragma unroll
        for (int it = 0; it < 2; ++it) {
            int m = it * 32 + am;
            *(uint4*)(As + (akc * 64 + (m ^ akc)) * 8) = pa[it];
        }
        #pragma unroll
        for (int it = 0; it < 6; ++it) {
            int n = it * 32 + bn;
            int phys = bkc * 192 + (n ^ bkc);
            *(uint4*)(Bs0 + phys * 8) = pb[it];
            if constexpr (BSPLIT)
                *(uint4*)(Bs1 + phys * 8) = pb2[it];
        }
        __syncthreads();

        // prefetch next k-slab during compute
        if (k0 + 64 < K) {
            #pragma unroll
            for (int it = 0; it < 2; ++it)
                pa[it] = *(const uint4*)(A + (size_t)(m0 + it * 32 + am) * K + k0 + 64 + akc * 8);
            #pragma unroll
            for (int it = 0; it < 6; ++it) {
                pb[it] = *(const uint4*)(Bt_h + (size_t)(n0 + it * 32 + bn) * K + k0 + 64 + bkc * 8);
                if constexpr (BSPLIT)
                    pb2[it] = *(const uint4*)(Bt_l + (size_t)(n0 + it * 32 + bn) * K + k0 + 64 + bkc * 8);
            }
        }

        #pragma unroll
        for (int kt2 = 0; kt2 < 2; ++kt2) {
            const int kc = kt2 * 4 + fq;
            bf16x8 ah[2], bh[6];
            #pragma unroll
            for (int mi = 0; mi < 2; ++mi)
                ah[mi] = *(const bf16x8*)(As + (kc * 64 + ((wm + mi * 16 + fm) ^ kc)) * 8);
            #pragma unroll
            for (int ni = 0; ni < 6; ++ni)
                bh[ni] = *(const bf16x8*)(Bs0 + (kc * 192 + ((wn + ni * 16 + fm) ^ kc)) * 8);
            #pragma unroll
            for (int mi = 0; mi < 2; ++mi)
                #pragma unroll
                for (int ni = 0; ni < 6; ++ni)
                    acc[mi][ni] = __builtin_amdgcn_mfma_f32_16x16x32_bf16(
                        ah[mi], bh[ni], acc[mi][ni], 0, 0, 0);
            if constexpr (BSPLIT) {
                bf16x8 bl[6];
                #pragma unroll
                for (int ni = 0; ni < 6; ++ni)
                    bl[ni] = *(const bf16x8*)(Bs1 + (kc * 192 + ((wn + ni * 16 + fm) ^ kc)) * 8);
                #pragma unroll
                for (int mi = 0; mi < 2; ++mi)
                    #pragma unroll
                    for (int ni = 0; ni < 6; ++ni)
                        acc[mi][ni] = __builtin_amdgcn_mfma_f32_16x16x32_bf16(
                            ah[mi], bl[ni], acc[mi][ni], 0, 0, 0);
            }
        }
        __syncthreads();
    }

    float bv[6];
    #pragma unroll
    for (int ni = 0; ni < 6; ++ni) bv[ni] = bias[n0 + wn + ni * 16 + fm];

    if constexpr (OUTBF) {
        // LDS-transpose epilogue: fp32 buf [32 rows][204 pad], then packed
        // bf16 uint4 stores (8 cols / thread-chunk), fully coalesced.
        float* ebuf = (float*)Lraw;                    // 32*204*4 = 26112 B
        #pragma unroll
        for (int hh = 0; hh < 2; ++hh) {
            if ((w & 1) == hh) {
                #pragma unroll
                for (int mi = 0; mi < 2; ++mi)
                    #pragma unroll
                    for (int ni = 0; ni < 6; ++ni)
                        #pragma unroll
                        for (int r = 0; r < 4; ++r)
                            ebuf[(mi * 16 + fq * 4 + r) * 204 + wn + ni * 16 + fm] =
                                acc[mi][ni][r] + bv[ni];
            }
            __syncthreads();
            #pragma unroll
            for (int it = 0; it < 3; ++it) {
                int flat = it * 256 + tid;             // 32 rows x 24 col-chunks
                int row = flat / 24, c8 = flat - row * 24;
                float4 a = *(const float4*)(ebuf + row * 204 + c8 * 8);
                float4 b = *(const float4*)(ebuf + row * 204 + c8 * 8 + 4);
                uint4 o;
                o.x = pack2(f2bf(a.x), f2bf(a.y));
                o.y = pack2(f2bf(a.z), f2bf(a.w));
                o.z = pack2(f2bf(b.x), f2bf(b.y));
                o.w = pack2(f2bf(b.z), f2bf(b.w));
                *(uint4*)((ushort_t*)Cout + (size_t)(m0 + hh * 32 + row) * N + n0 + c8 * 8) = o;
            }
            __syncthreads();
        }
    } else {
        #pragma unroll
        for (int ni = 0; ni < 6; ++ni) {
            const int col = n0 + wn + ni * 16 + fm;
            #pragma unroll
            for (int mi = 0; mi < 2; ++mi) {
                const int rbase = m0 + wm + mi * 16 + fq * 4;
                #pragma unroll
                for (int r = 0; r < 4; ++r)
                    ((float*)Cout)[(size_t)(rbase + r) * N + col] = acc[mi][ni][r] + bv[ni];
            }
        }
    }
}

// ---------------------------------------------------------------------------
// Neighborhood attention v4 — MFMA flash-style (unchanged from R7).
// ---------------------------------------------------------------------------
__global__ __launch_bounds__(384, 5) void na2d_kernel(
    const ushort_t* __restrict__ qkv, const ushort_t* __restrict__ vT,
    ushort_t* __restrict__ attn)
{
    __shared__ ushort_t Kb[2][96 * 40];    // [col][pad40], chunk-XOR swizzle
    __shared__ ushort_t Vtb[2][32 * 104];  // [dim][pad104]
    __shared__ ushort_t Pb[6][16 * 40];    // per-wave P, [pix][pad40] swizzled

    int idx = blockIdx.x;
    const int g = idx % 3; idx /= 3;       // g fastest: XCD load balance
    const int h = idx & 1; idx >>= 1;
    const int i = idx % 96;
    const int b = idx / 96;

    const int K = 7 + 2 * g, cc = K >> 1;
    int si = i - cc; if (si < 0) si = 0; if (si > H_ - K) si = H_ - K;

    const int tid = threadIdx.x;
    const int w = tid >> 6, lane = tid & 63;
    const int fm = lane & 15, fq = lane >> 4;
    const int pixbase = w * 16;

    int cb = (pixbase - cc) & ~7;          // aligned union-window base
    if (cb < 0) cb = 0; if (cb > 64) cb = 64;
    const int col0 = cb + fm, col1 = cb + 16 + fm;

    int sj[4];
    #pragma unroll
    for (int r = 0; r < 4; ++r) {
        int jj = pixbase + fq * 4 + r - cc;
        if (jj < 0) jj = 0; if (jj > W_ - K) jj = W_ - K;
        sj[r] = jj;
    }

    const size_t rowstride = (size_t)W_ * QKVC;
    const bf16x8 qfrag = *(const bf16x8*)(
        qkv + (size_t)(b * H_ + i) * rowstride + (size_t)(pixbase + fm) * QKVC
        + g * 192 + h * 32 + fq * 8);

    const int scol = tid >> 2, sch = tid & 3;
    const size_t kgoff = (size_t)scol * QKVC + g * 192 + 64 + h * 32 + sch * 8;
    const int klds = scol * 40 + ((sch ^ (scol & 3)) << 3);
    const int vd = tid / 12, vc8 = tid - vd * 12;
    const int vlds = vd * 104 + vc8 * 8;
    const size_t vslice = ((size_t)((b * H_ + si) * 6) + g * 2 + h) * 3072;

    f32x4 y0 = {0.f, 0.f, 0.f, 0.f}, y1 = {0.f, 0.f, 0.f, 0.f};
    float lacc[4] = {0.f, 0.f, 0.f, 0.f};

    uint4 kv = *(const uint4*)(qkv + (size_t)(b * H_ + si) * rowstride + kgoff);
    uint4 vv = *(const uint4*)(vT + vslice + (size_t)tid * 8);

    for (int t = 0; t < K; ++t) {
        *(uint4*)&Kb[t & 1][klds] = kv;
        *(uint4*)&Vtb[t & 1][vlds] = vv;
        if (t + 1 < K) {
            kv = *(const uint4*)(qkv + (size_t)(b * H_ + si + t + 1) * rowstride + kgoff);
            vv = *(const uint4*)(vT + vslice + (size_t)(t + 1) * 18432 + (size_t)tid * 8);
        }
        __syncthreads();

        bf16x8 kf0 = *(const bf16x8*)&Kb[t & 1][col0 * 40 + ((fq ^ (col0 & 3)) << 3)];
        bf16x8 kf1 = *(const bf16x8*)&Kb[t & 1][col1 * 40 + ((fq ^ (col1 & 3)) << 3)];
        f32x4 s0 = __builtin_amdgcn_mfma_f32_16x16x32_bf16(
            qfrag, kf0, (f32x4){0.f, 0.f, 0.f, 0.f}, 0, 0, 0);
        f32x4 s1 = __builtin_amdgcn_mfma_f32_16x16x32_bf16(
            qfrag, kf1, (f32x4){0.f, 0.f, 0.f, 0.f}, 0, 0, 0);

        #pragma unroll
        for (int r = 0; r < 4; ++r) {
            float e0 = __expf(s0[r] * SCALE);
            float e1 = __expf(s1[r] * SCALE);
            e0 = ((unsigned)(col0 - sj[r]) < (unsigned)K) ? e0 : 0.f;
            e1 = ((unsigned)(col1 - sj[r]) < (unsigned)K) ? e1 : 0.f;
            unsigned short p0 = f2bf(e0), p1 = f2bf(e1);
            lacc[r] += bf2f(p0) + bf2f(p1);
            const int m = fq * 4 + r;
            Pb[w][m * 40 + (((fm >> 3) ^ (m & 3)) << 3) + (fm & 7)] = p0;
            Pb[w][m * 40 + ((((fm >> 3) + 2) ^ (m & 3)) << 3) + (fm & 7)] = p1;
        }

        bf16x8 pf = *(const bf16x8*)&Pb[w][fm * 40 + ((fq ^ (fm & 3)) << 3)];
        bf16x8 vf0 = *(const bf16x8*)&Vtb[t & 1][fm * 104 + cb + fq * 8];
        bf16x8 vf1 = *(const bf16x8*)&Vtb[t & 1][(16 + fm) * 104 + cb + fq * 8];
        y0 = __builtin_amdgcn_mfma_f32_16x16x32_bf16(pf, vf0, y0, 0, 0, 0);
        y1 = __builtin_amdgcn_mfma_f32_16x16x32_bf16(pf, vf1, y1, 0, 0, 0);
    }

    #pragma unroll
    for (int r = 0; r < 4; ++r) {
        float l = lacc[r];
        l += __shfl_xor(l, 1); l += __shfl_xor(l, 2);
        l += __shfl_xor(l, 4); l += __shfl_xor(l, 8);
        const float inv = 1.f / l;
        const int j = pixbase + fq * 4 + r;
        const size_t o = (size_t)((b * H_ + i) * W_ + j) * C_ + g * 64 + h * 32 + fm;
        attn[o]      = f2bf(y0[r] * inv);
        attn[o + 16] = f2bf(y1[r] * inv);
    }
}

// ---------------------------------------------------------------------------
extern "C" void kernel_launch(void* const* d_in, const int* in_sizes, int n_in,
                              void* d_out, int out_size, void* d_ws, size_t ws_size,
                              hipStream_t stream)
{
    const float* x      = (const float*)d_in[0];
    const float* w_qkv  = (const float*)d_in[1];
    const float* b_qkv  = (const float*)d_in[2];
    const float* w_proj = (const float*)d_in[3];
    const float* b_proj = (const float*)d_in[4];
    float* out = (float*)d_out;

    // Workspace: [qkvh 42.5MB][xh/attn bf16 14.2MB aliased][weights][vT 14.2MB]
    char* ws = (char*)d_ws;
    ushort_t* qkvh  = (ushort_t*)ws;
    char*     reg1  = ws + (size_t)NPIX * QKVC * 2;
    ushort_t* xh    = (ushort_t*)reg1;            // dead after GEMM1
    ushort_t* attn  = (ushort_t*)reg1;            // aliases xh
    char*     wbase = reg1 + (size_t)NPIX * C_ * 2;
    ushort_t* wqt   = (ushort_t*)wbase;
    ushort_t* wpt_h = (ushort_t*)(wbase + 576 * 192 * 2);
    ushort_t* wpt_l = (ushort_t*)(wbase + 576 * 192 * 2 + 192 * 192 * 2);
    ushort_t* vT    = (ushort_t*)(wbase + 576 * 192 * 2 + 2 * 192 * 192 * 2);

    convert_x_kernel<<<(NPIX * C_ / 4 + 255) / 256, 256, 0, stream>>>(
        x, xh, NPIX * C_ / 4);
    convert_w_kernel<<<(576 * 192 + 192 * 192 + 255) / 256, 256, 0, stream>>>(
        w_qkv, w_proj, wqt, wpt_h, wpt_l);

    // 1) qkv = x @ w_qkv + b_qkv (bf16 out, LDS-transpose epilogue)
    gemm_mfma3_kernel<false, true><<<(NPIX / 64) * (QKVC / 192), 256, 0, stream>>>(
        xh, wqt, nullptr, b_qkv, qkvh, NPIX, QKVC, C_);

    // 1b) vT = transposed v slices (coalesced LDS transpose)
    vt_kernel<<<B_ * H_, 192, 0, stream>>>(qkvh, vT);

    // 2) neighborhood attention (MFMA flash-style)
    na2d_kernel<<<2304, 384, 0, stream>>>(qkvh, vT, attn);

    // 3) out = attn @ w_proj + b_proj (A bf16, B split-bf16 2-pass)
    gemm_mfma3_kernel<true, false><<<(NPIX / 64) * (C_ / 192), 256, 0, stream>>>(
        attn, wpt_h, wpt_l, b_proj, out, NPIX, C_, C_);
}